// Round 14
// baseline (557.549 us; speedup 1.0000x reference)
//
#include <hip/hip_runtime.h>
#include <hip/hip_bf16.h>

#define NN 50000
#define NE 800000
#define DN 160
#define DE 32
#define NP 50176              /* NN padded to 196*256 */

typedef __attribute__((ext_vector_type(2))) _Float16 f16x2;
typedef __attribute__((ext_vector_type(8))) _Float16 f16x8;
typedef __attribute__((ext_vector_type(4))) float f32x4;
typedef __attribute__((ext_vector_type(4))) unsigned short u16x4;

#define R2 0.81649658092772603f   /* sqrt(2/3): W2 rel scale */
#define R4 1.41421356237309515f   /* sqrt(2):   W4 rel scale */
#define SC (1.0f/32.0f)           /* global scale folded into weights */

#define XST 172                   /* xls row stride (u16) */
#define EST 38                    /* els row stride (u16) */

union AF { f16x2 p[4]; f16x8 v; };

__device__ __forceinline__ unsigned short f16bits(float f) {
    union { _Float16 h; unsigned short s; } u;
    u.h = (_Float16)f;
    return u.s;
}

// async global->LDS, 16B per lane; dst is wave-uniform base (HW adds lane*16)
__device__ __forceinline__ void load_lds16(const void* g, void* l) {
    __builtin_amdgcn_global_load_lds(
        (const __attribute__((address_space(1))) unsigned int*)g,
        (__attribute__((address_space(3))) unsigned int*)l, 16, 0, 0);
}

// ---- x -> f16 copy (one-time) ----
__global__ __launch_bounds__(256) void xprep_kernel(const float* __restrict__ x,
                                                    unsigned short* __restrict__ xb) {
    int i = blockIdx.x * 256 + threadIdx.x;   // float4 index
    if (i < NN * DN / 4) {
        const float4 v = reinterpret_cast<const float4*>(x)[i];
        u16x4 p; p[0] = f16bits(v.x); p[1] = f16bits(v.y); p[2] = f16bits(v.z); p[3] = f16bits(v.w);
        reinterpret_cast<u16x4*>(xb)[i] = p;
    }
}

// ---- zero T + histogram counters ----
__global__ __launch_bounds__(256) void zero_kernel(float* __restrict__ T,
                                                   int* __restrict__ cnt) {
    int i = blockIdx.x * 256 + threadIdx.x;
    if (i < NN * DN) T[i] = 0.0f;
    if (i < NP) cnt[i] = 0;
}

__global__ __launch_bounds__(256) void hist_kernel(const int* __restrict__ eidx,
                                                   int* __restrict__ cnt) {
    int e = blockIdx.x * 256 + threadIdx.x;
    if (e < NE) atomicAdd(&cnt[eidx[e]], 1);
}

__global__ __launch_bounds__(256) void scan1_kernel(const int* __restrict__ cnt,
                                                    int* __restrict__ cursor,
                                                    int* __restrict__ bsum) {
    __shared__ int s[256];
    const int t = threadIdx.x;
    const int i = blockIdx.x * 256 + t;
    const int v = cnt[i];
    s[t] = v; __syncthreads();
    for (int off = 1; off < 256; off <<= 1) {
        int u = (t >= off) ? s[t - off] : 0;
        __syncthreads(); s[t] += u; __syncthreads();
    }
    cursor[i] = s[t] - v;
    if (t == 255) bsum[blockIdx.x] = s[255];
}

__global__ __launch_bounds__(256) void scan2_kernel(int* __restrict__ bsum) {
    __shared__ int s[256];
    const int t = threadIdx.x;
    const int v = (t < 196) ? bsum[t] : 0;
    s[t] = v; __syncthreads();
    for (int off = 1; off < 256; off <<= 1) {
        int u = (t >= off) ? s[t - off] : 0;
        __syncthreads(); s[t] += u; __syncthreads();
    }
    if (t < 196) bsum[t] = s[t] - v;
}

__global__ __launch_bounds__(256) void scan3_kernel(int* __restrict__ cursor,
                                                    const int* __restrict__ bsum) {
    int i = blockIdx.x * 256 + threadIdx.x;
    cursor[i] += bsum[blockIdx.x];
}

__global__ __launch_bounds__(256) void scatter_kernel(const int* __restrict__ eidx,
                                                      int* __restrict__ cursor,
                                                      int* __restrict__ sorted) {
    int e = blockIdx.x * 256 + threadIdx.x;
    if (e < NE) {
        int pos = atomicAdd(&cursor[eidx[e]], 1);
        sorted[pos] = e;
    }
}

// ---- edge-TP weights: f16, pre-scaled, MFMA 16x16x32 B-frag layout,
//      tt-CONSECUTIVE: id = ((tt*6 + s)*64 + lane)*8 + j ----
__global__ __launch_bounds__(256) void wprep_edge_kernel(
    const float* __restrict__ W1, const float* __restrict__ W2,
    const float* __restrict__ W3, const float* __restrict__ W4,
    unsigned short* __restrict__ Wh)
{
    int id = blockIdx.x * 256 + threadIdx.x;   // 73728 total
    if (id >= 73728) return;
    int j = id & 7, l = (id >> 3) & 63, st = id >> 9;  // st = tt*6+s
    int tt = st / 6, s = st % 6;
    int k = 32 * tt + 8 * (l >> 4) + j;
    float w;
    if (s < 4) {
        int c = s * 16 + (l & 15);
        if (k < 512) { int a = k >> 3, b = k & 7; w = W1[(a*8+b)*64 + c] * SC; }
        else { int k2 = k - 512; int a = k2 >> 3, b = k2 & 7; w = W2[(a*8+b)*64 + c] * (R2*SC); }
    } else {
        int c = (s - 4) * 16 + (l & 15);
        if (k < 512) { int a = k >> 3, b = k & 7; w = W3[(a*8+b)*32 + c] * SC; }
        else { int k2 = k - 512; int a = k2 >> 3, b = k2 & 7; w = W4[(a*8+b)*32 + c] * (R4*SC); }
    }
    Wh[id] = f16bits(w);
}

// ---- Wc = Wm @ Wu_bot (fp32), bc = bm @ Wu_bot ----
__global__ __launch_bounds__(256) void wcomp_kernel(
    const float* __restrict__ Wm, const float* __restrict__ bm,
    const float* __restrict__ Wu, float* __restrict__ Wc, float* __restrict__ bc)
{
    int id = blockIdx.x * 256 + threadIdx.x;
    if (id < 160 * 160) {
        int k = id / 160, c = id % 160;
        float s = 0.0f;
        for (int h = 0; h < 160; ++h) s = fmaf(Wm[k*160 + h], Wu[(160 + h)*160 + c], s);
        Wc[id] = s;
    }
    if (id < 160) {
        float s = 0.0f;
        for (int h = 0; h < 160; ++h) s = fmaf(bm[h], Wu[(160 + h)*160 + id], s);
        bc[id] = s;
    }
}

// ---- node-GEMM weights (f16): [Wu_top(160); Wc permuted to T's i-major layout] ----
__global__ __launch_bounds__(256) void wprep_node_kernel(
    const float* __restrict__ Wu, const float* __restrict__ Wc,
    unsigned short* __restrict__ Wn)
{
    int id = blockIdx.x * 256 + threadIdx.x;   // 51200 total
    if (id >= 51200) return;
    int j = id & 7, l = (id >> 3) & 63, tn = id >> 9;  // tn = n16*10 + tk
    int tk = tn % 10, n16 = tn / 10;
    int c = n16 * 16 + (l & 15);
    int k = 32 * tk + 8 * (l >> 4) + j;
    float w;
    if (k < 160) {
        w = Wu[k * 160 + c];
    } else {
        int tcol = k - 160;  // T col: [0,64)=s ; 64+i*32+cc (i-major v)
        int orig = (tcol < 64) ? tcol : 64 + ((tcol - 64) & 31) * 3 + ((tcol - 64) >> 5);
        w = Wc[orig * 160 + c];
    }
    Wn[id] = f16bits(w);
}

// A-fragment formation for k-tile tt (uniform branch)
__device__ __forceinline__ void makeA(int tt, int g, int er,
    const unsigned short* __restrict__ xls,
    const f16x2 es2[4], const f16x2 ev2[3][4],
    AF& aS, AF& aV0, AF& aV1, AF& aV2)
{
    if (tt < 16) {
        const _Float16 xa = *reinterpret_cast<const _Float16*>(&xls[er*XST + 4*tt + g]);
        const f16x2 xa2 = (f16x2){xa, xa};
        #pragma unroll
        for (int p = 0; p < 4; ++p) {
            aS.p[p]  = xa2 * es2[p];
            aV0.p[p] = xa2 * ev2[0][p];
            aV1.p[p] = xa2 * ev2[1][p];
            aV2.p[p] = xa2 * ev2[2][p];
        }
    } else {
        const int a = 4 * (tt - 16) + g;
        const _Float16 x0 = *reinterpret_cast<const _Float16*>(&xls[er*XST + 64 + a*3 + 0]);
        const _Float16 x1 = *reinterpret_cast<const _Float16*>(&xls[er*XST + 64 + a*3 + 1]);
        const _Float16 x2 = *reinterpret_cast<const _Float16*>(&xls[er*XST + 64 + a*3 + 2]);
        const f16x2 x02 = (f16x2){x0, x0};
        const f16x2 x12 = (f16x2){x1, x1};
        const f16x2 x22 = (f16x2){x2, x2};
        #pragma unroll
        for (int p = 0; p < 4; ++p) {
            f16x2 d = x02 * ev2[0][p];
            d += x12 * ev2[1][p];
            d += x22 * ev2[2][p];
            aS.p[p]  = d;                   // z2 dot (r2 folded in W)
            aV0.p[p] = x02 * es2[p];        // z4 (r4 folded in W)
            aV1.p[p] = x12 * es2[p];
            aV2.p[p] = x22 * es2[p];
        }
    }
}

// ---- per-edge TP via f16 MFMA, dest-sorted edges.
//      Weights staged per-block into 4-deep LDS ring via global_load_lds.
//      K-loop uses COUNTED vmcnt + raw s_barrier (T3/T4): tiles t+1,t+2's
//      loads stay in flight across the barrier (no vmcnt(0) drain). ----
template<int UXB>
__global__ __launch_bounds__(256, 3) void edge_kernel(
    const float* __restrict__ x, const unsigned short* __restrict__ xb,
    const int* __restrict__ eidx, const float* __restrict__ ea,
    const unsigned short* __restrict__ Wh,
    const int* __restrict__ sorted, float* __restrict__ T)
{
    // xls 22016 B | els 4864 B | wbuf 4x6144 B = 51456 B (3 blocks/CU)
    // epilogue accw[32][161] f32 (20608 B) overlays xls
    __shared__ __align__(16) char smem[64*XST*2 + 64*EST*2 + 4*3072*2];
    __shared__ int rowls[64];
    __shared__ int colls[64];
    __shared__ int sels[64];

    unsigned short* xls  = (unsigned short*)smem;                        // [64][XST] f16
    unsigned short* els  = (unsigned short*)(smem + 64*XST*2);           // [64][EST] f16
    unsigned short* wbuf = (unsigned short*)(smem + 64*XST*2 + 64*EST*2); // [4][3072] f16

    const int t = threadIdx.x;
    const int base = blockIdx.x * 64;

    if (t < 64) {
        const int se = sorted[base + t];
        sels[t] = se;
        rowls[t] = eidx[se];
        colls[t] = eidx[NE + se];
    }
    __syncthreads();

    if (UXB) {
        for (int j = t; j < 64 * 40; j += 256) {
            int m = j / 40, q = j - m * 40;
            const u16x4 v = *reinterpret_cast<const u16x4*>(xb + (size_t)colls[m] * DN + q * 4);
            *reinterpret_cast<u16x4*>(&xls[m*XST + q*4]) = v;
        }
    } else {
        for (int j = t; j < 64 * 40; j += 256) {
            int m = j / 40, q = j - m * 40;
            const float4 v = *reinterpret_cast<const float4*>(x + (size_t)colls[m] * DN + q * 4);
            u16x4 p; p[0] = f16bits(v.x); p[1] = f16bits(v.y); p[2] = f16bits(v.z); p[3] = f16bits(v.w);
            *reinterpret_cast<u16x4*>(&xls[m*XST + q*4]) = p;
        }
    }
    // e staging with transpose of the vector part
    for (int j = t; j < 64 * 8; j += 256) {
        int m = j >> 3, q = j & 7;
        const float4 v = *reinterpret_cast<const float4*>(ea + (size_t)sels[m] * DE + q * 4);
        #pragma unroll
        for (int z = 0; z < 4; ++z) {
            int p = q * 4 + z;
            float val = (z == 0) ? v.x : (z == 1) ? v.y : (z == 2) ? v.z : v.w;
            int dst = (p < 8) ? p : 8 + ((p - 8) % 3) * 8 + (p - 8) / 3;
            els[m*EST + dst] = f16bits(val);
        }
    }

    const int lane = t & 63;
    const int wv = t >> 6;        // 0..3
    const int r = lane & 15;      // A row / B col / C col
    const int g = lane >> 4;      // k-group
    const int er = wv * 16 + r;   // edge owning this lane's A row

    // stage weights of k-tile tt into wbuf[tt&3]: waves 0,1 load 2 chunks; 2,3 load 1
    #define STAGE_W(tt)                                                            \
        do {                                                                       \
            const unsigned short* wsrc = Wh + (size_t)(tt) * 3072;                 \
            unsigned short* wdst = wbuf + ((tt) & 3) * 3072;                       \
            if (wv < 2) {                                                          \
                load_lds16(wsrc + (2*wv)*512 + lane*8, wdst + (2*wv)*512);         \
                load_lds16(wsrc + (2*wv+1)*512 + lane*8, wdst + (2*wv+1)*512);     \
            } else {                                                               \
                load_lds16(wsrc + (wv+2)*512 + lane*8, wdst + (wv+2)*512);         \
            }                                                                      \
        } while (0)

    STAGE_W(0); STAGE_W(1); STAGE_W(2);   // prologue: 3-deep

    __syncthreads();   // staging + prologue weight tiles all land (one-time drain)

    f16x2 es2[4], ev2[3][4];
    #pragma unroll
    for (int p = 0; p < 4; ++p) {
        es2[p] = *reinterpret_cast<const f16x2*>(&els[er*EST + 2*p]);
        #pragma unroll
        for (int i = 0; i < 3; ++i)
            ev2[i][p] = *reinterpret_cast<const f16x2*>(&els[er*EST + 8 + i*8 + 2*p]);
    }

    f32x4 accS[4], accV[3][2];
    #pragma unroll
    for (int n = 0; n < 4; ++n) accS[n] = (f32x4){0.f, 0.f, 0.f, 0.f};
    #pragma unroll
    for (int i = 0; i < 3; ++i)
        #pragma unroll
        for (int n = 0; n < 2; ++n) accV[i][n] = (f32x4){0.f, 0.f, 0.f, 0.f};

    for (int tt = 0; tt < 24; ++tt) {
        if (tt) {
            // counted wait: tile tt's loads (issued 3 iters ago) must land;
            // tiles tt+1, tt+2's loads may stay in flight across the barrier.
            if (wv < 2) asm volatile("s_waitcnt vmcnt(4)" ::: "memory");
            else        asm volatile("s_waitcnt vmcnt(2)" ::: "memory");
            __builtin_amdgcn_s_barrier();
            __builtin_amdgcn_sched_barrier(0);
        }
        if (tt + 3 < 24) STAGE_W(tt + 3);   // after barrier: buf[(tt-1)&3] is free

        const unsigned short* wb = wbuf + (tt & 3) * 3072 + lane * 8;
        f16x8 B[6];
        #pragma unroll
        for (int n = 0; n < 6; ++n)
            B[n] = *reinterpret_cast<const f16x8*>(wb + n * 512);  // ds_read_b128

        AF aS, aV0, aV1, aV2;
        makeA(tt, g, er, xls, es2, ev2, aS, aV0, aV1, aV2);

        accS[0] = __builtin_amdgcn_mfma_f32_16x16x32_f16(aS.v,  B[0], accS[0],0,0,0);
        accS[1] = __builtin_amdgcn_mfma_f32_16x16x32_f16(aS.v,  B[1], accS[1],0,0,0);
        accS[2] = __builtin_amdgcn_mfma_f32_16x16x32_f16(aS.v,  B[2], accS[2],0,0,0);
        accS[3] = __builtin_amdgcn_mfma_f32_16x16x32_f16(aS.v,  B[3], accS[3],0,0,0);
        accV[0][0] = __builtin_amdgcn_mfma_f32_16x16x32_f16(aV0.v, B[4], accV[0][0],0,0,0);
        accV[0][1] = __builtin_amdgcn_mfma_f32_16x16x32_f16(aV0.v, B[5], accV[0][1],0,0,0);
        accV[1][0] = __builtin_amdgcn_mfma_f32_16x16x32_f16(aV1.v, B[4], accV[1][0],0,0,0);
        accV[1][1] = __builtin_amdgcn_mfma_f32_16x16x32_f16(aV1.v, B[5], accV[1][1],0,0,0);
        accV[2][0] = __builtin_amdgcn_mfma_f32_16x16x32_f16(aV2.v, B[4], accV[2][0],0,0,0);
        accV[2][1] = __builtin_amdgcn_mfma_f32_16x16x32_f16(aV2.v, B[5], accV[2][1],0,0,0);
    }
    #undef STAGE_W

    __syncthreads();   // full drain; reuse smem for acc (2 chunks of 32)
    float* accw = (float*)smem;  // [32][161]

    #pragma unroll
    for (int half = 0; half < 2; ++half) {
        if ((wv >> 1) == half) {
            const int lbase = (wv & 1) * 16 + g * 4;
            #pragma unroll
            for (int reg = 0; reg < 4; ++reg) {
                const int lrow = lbase + reg;
                #pragma unroll
                for (int n = 0; n < 4; ++n)
                    accw[lrow*161 + n*16 + r] = accS[n][reg];
                #pragma unroll
                for (int i = 0; i < 3; ++i)
                    #pragma unroll
                    for (int n = 0; n < 2; ++n)
                        accw[lrow*161 + 64 + i*32 + n*16 + r] = accV[i][n][reg];  // i-major
            }
        }
        __syncthreads();

        if (t < DN) {
            const int col = t;
            const int ebase = half * 32;
            float s = 0.0f;
            int rstart = 0;
            for (int e = 0; e < 32; ++e) {
                s += accw[e*161 + col];
                const int ge = ebase + e;
                if (e == 31 || rowls[ge] != rowls[ge + 1]) {
                    float* dst = T + (size_t)rowls[ge] * DN + col;
                    if (rstart == 0 || e == 31) atomicAdd(dst, s);  // chunk-boundary run
                    else *dst = s;                                   // interior: exclusive
                    s = 0.0f; rstart = e + 1;
                }
            }
        }
        __syncthreads();
    }
}

// ---- node update: out = x + [f16(x), f16(T)] @ Wn + bu + deg*bc ----
template<int UXB>
__global__ __launch_bounds__(256) void node_kernel(
    const float* __restrict__ x, const unsigned short* __restrict__ xb,
    float* __restrict__ T, const int* __restrict__ cnt,
    const unsigned short* __restrict__ Wn,
    const float* __restrict__ bu, const float* __restrict__ bc)
{
    __shared__ __align__(16) unsigned short A[64][328];  // 160 x | 160 T (f16)
    const int t = threadIdx.x;
    const int nb = blockIdx.x * 64;

    if (UXB) {
        for (int j = t; j < 64 * 40; j += 256) {   // x-part straight f16 copy
            int m = j / 40, q = j - m * 40;
            int row = nb + m; if (row >= NN) row = NN - 1;
            const u16x4 v = *reinterpret_cast<const u16x4*>(xb + (size_t)row * DN + q * 4);
            *reinterpret_cast<u16x4*>(&A[m][q*4]) = v;
        }
    } else {
        for (int j = t; j < 64 * 40; j += 256) {
            int m = j / 40, q = j - m * 40;
            int row = nb + m; if (row >= NN) row = NN - 1;
            const float4 v = *reinterpret_cast<const float4*>(x + (size_t)row * DN + q * 4);
            u16x4 p; p[0] = f16bits(v.x); p[1] = f16bits(v.y); p[2] = f16bits(v.z); p[3] = f16bits(v.w);
            *reinterpret_cast<u16x4*>(&A[m][q*4]) = p;
        }
    }
    for (int j = t; j < 64 * 40; j += 256) {       // T-part with cvt
        int m = j / 40, q = j - m * 40;
        int row = nb + m; if (row >= NN) row = NN - 1;
        const float4 v = *reinterpret_cast<const float4*>(T + (size_t)row * DN + q * 4);
        u16x4 p; p[0] = f16bits(v.x); p[1] = f16bits(v.y); p[2] = f16bits(v.z); p[3] = f16bits(v.w);
        *reinterpret_cast<u16x4*>(&A[m][160 + q*4]) = p;
    }
    __syncthreads();

    const int lane = t & 63;
    const int wv = t >> 6;
    const int r = lane & 15, g = lane >> 4;
    const int er = wv * 16 + r;

    f32x4 acc[10];
    #pragma unroll
    for (int n = 0; n < 10; ++n) acc[n] = (f32x4){0.f, 0.f, 0.f, 0.f};

    for (int tk = 0; tk < 10; ++tk) {
        const f16x8 a = *reinterpret_cast<const f16x8*>(&A[er][32 * tk + 8 * g]);
        #pragma unroll
        for (int n = 0; n < 10; ++n) {
            const f16x8 b = *reinterpret_cast<const f16x8*>(Wn + ((size_t)(n * 10 + tk) * 64 + lane) * 8);
            acc[n] = __builtin_amdgcn_mfma_f32_16x16x32_f16(a, b, acc[n], 0, 0, 0);
        }
    }

    #pragma unroll
    for (int reg = 0; reg < 4; ++reg) {
        const int nrow = nb + wv * 16 + g * 4 + reg;
        if (nrow < NN) {
            const float dg = (float)cnt[nrow];
            #pragma unroll
            for (int n = 0; n < 10; ++n) {
                const int c = n * 16 + r;
                T[(size_t)nrow * DN + c] =
                    acc[n][reg] + x[(size_t)nrow * DN + c] + bu[c] + dg * bc[c];
            }
        }
    }
}

extern "C" void kernel_launch(void* const* d_in, const int* in_sizes, int n_in,
                              void* d_out, int out_size, void* d_ws, size_t ws_size,
                              hipStream_t stream) {
    const float* xf   = (const float*)d_in[0];
    const int*   eidx = (const int*)d_in[1];
    const float* ea   = (const float*)d_in[2];
    const float* W1 = (const float*)d_in[4];
    const float* W2 = (const float*)d_in[5];
    const float* W3 = (const float*)d_in[6];
    const float* W4 = (const float*)d_in[7];
    const float* Wm = (const float*)d_in[8];
    const float* bm = (const float*)d_in[9];
    const float* Wu = (const float*)d_in[10];
    const float* bu = (const float*)d_in[11];

    float* out = (float*)d_out;   // doubles as tp-accumulator T

    char* ws = (char*)d_ws;
    int*            cnt    = (int*)ws;                              // 200 KB
    int*            cursor = (int*)(ws + (256 << 10));              // 200 KB
    int*            sorted = (int*)(ws + (512 << 10));              // 3.2 MB
    int*            bsum   = (int*)(ws + (3968 << 10));             // 1 KB
    unsigned short* Wh     = (unsigned short*)(ws + (4096 << 10));  // 144 KB f16 edge W
    float*          Wc     = (float*)(ws + (4352 << 10));           // 100 KB
    float*          bc     = (float*)(ws + (4480 << 10));           // 640 B
    unsigned short* Wn     = (unsigned short*)(ws + (4608 << 10));  // 100 KB f16 node W
    unsigned short* xb     = (unsigned short*)(ws + (4864 << 10));  // 16 MB f16 x

    const bool uxb = ws_size >= ((size_t)(4864 + 16000) << 10);

    wcomp_kernel<<<100, 256, 0, stream>>>(Wm, bm, Wu, Wc, bc);
    wprep_node_kernel<<<200, 256, 0, stream>>>(Wu, Wc, Wn);
    wprep_edge_kernel<<<288, 256, 0, stream>>>(W1, W2, W3, W4, Wh);
    if (uxb) xprep_kernel<<<(NN * DN / 4 + 255) / 256, 256, 0, stream>>>(xf, xb);
    zero_kernel<<<(NN * DN + 255) / 256, 256, 0, stream>>>(out, cnt);
    hist_kernel<<<NE / 256, 256, 0, stream>>>(eidx, cnt);
    scan1_kernel<<<NP / 256, 256, 0, stream>>>(cnt, cursor, bsum);
    scan2_kernel<<<1, 256, 0, stream>>>(bsum);
    scan3_kernel<<<NP / 256, 256, 0, stream>>>(cursor, bsum);
    scatter_kernel<<<NE / 256, 256, 0, stream>>>(eidx, cursor, sorted);
    if (uxb) {
        edge_kernel<1><<<NE / 64, 256, 0, stream>>>(xf, xb, eidx, ea, Wh, sorted, out);
        node_kernel<1><<<(NN + 63) / 64, 256, 0, stream>>>(xf, xb, out, cnt, Wn, bu, bc);
    } else {
        edge_kernel<0><<<NE / 64, 256, 0, stream>>>(xf, xb, eidx, ea, Wh, sorted, out);
        node_kernel<0><<<(NN + 63) / 64, 256, 0, stream>>>(xf, xb, out, cnt, Wn, bu, bc);
    }
}

// Round 15
// 524.741 us; speedup vs baseline: 1.0625x; 1.0625x over previous
//
#include <hip/hip_runtime.h>
#include <hip/hip_bf16.h>

#define NN 50000
#define NE 800000
#define DN 160
#define DE 32
#define NP 50176              /* NN padded to 196*256 */

typedef __attribute__((ext_vector_type(2))) _Float16 f16x2;
typedef __attribute__((ext_vector_type(8))) _Float16 f16x8;
typedef __attribute__((ext_vector_type(4))) float f32x4;
typedef __attribute__((ext_vector_type(4))) unsigned short u16x4;

#define R2 0.81649658092772603f   /* sqrt(2/3): W2 rel scale */
#define R4 1.41421356237309515f   /* sqrt(2):   W4 rel scale */
#define SC (1.0f/32.0f)           /* global scale folded into weights */

#define XST 172                   /* xls row stride (u16) */
#define EST 38                    /* els row stride (u16) */

union AF { f16x2 p[4]; f16x8 v; };

__device__ __forceinline__ unsigned short f16bits(float f) {
    union { _Float16 h; unsigned short s; } u;
    u.h = (_Float16)f;
    return u.s;
}

// async global->LDS, 16B per lane; dst is wave-uniform base (HW adds lane*16)
__device__ __forceinline__ void load_lds16(const void* g, void* l) {
    __builtin_amdgcn_global_load_lds(
        (const __attribute__((address_space(1))) unsigned int*)g,
        (__attribute__((address_space(3))) unsigned int*)l, 16, 0, 0);
}

// ---- x -> f16 copy (one-time) ----
__global__ __launch_bounds__(256) void xprep_kernel(const float* __restrict__ x,
                                                    unsigned short* __restrict__ xb) {
    int i = blockIdx.x * 256 + threadIdx.x;   // float4 index
    if (i < NN * DN / 4) {
        const float4 v = reinterpret_cast<const float4*>(x)[i];
        u16x4 p; p[0] = f16bits(v.x); p[1] = f16bits(v.y); p[2] = f16bits(v.z); p[3] = f16bits(v.w);
        reinterpret_cast<u16x4*>(xb)[i] = p;
    }
}

// ---- zero T + histogram counters ----
__global__ __launch_bounds__(256) void zero_kernel(float* __restrict__ T,
                                                   int* __restrict__ cnt) {
    int i = blockIdx.x * 256 + threadIdx.x;
    if (i < NN * DN) T[i] = 0.0f;
    if (i < NP) cnt[i] = 0;
}

__global__ __launch_bounds__(256) void hist_kernel(const int* __restrict__ eidx,
                                                   int* __restrict__ cnt) {
    int e = blockIdx.x * 256 + threadIdx.x;
    if (e < NE) atomicAdd(&cnt[eidx[e]], 1);
}

__global__ __launch_bounds__(256) void scan1_kernel(const int* __restrict__ cnt,
                                                    int* __restrict__ cursor,
                                                    int* __restrict__ bsum) {
    __shared__ int s[256];
    const int t = threadIdx.x;
    const int i = blockIdx.x * 256 + t;
    const int v = cnt[i];
    s[t] = v; __syncthreads();
    for (int off = 1; off < 256; off <<= 1) {
        int u = (t >= off) ? s[t - off] : 0;
        __syncthreads(); s[t] += u; __syncthreads();
    }
    cursor[i] = s[t] - v;
    if (t == 255) bsum[blockIdx.x] = s[255];
}

__global__ __launch_bounds__(256) void scan2_kernel(int* __restrict__ bsum) {
    __shared__ int s[256];
    const int t = threadIdx.x;
    const int v = (t < 196) ? bsum[t] : 0;
    s[t] = v; __syncthreads();
    for (int off = 1; off < 256; off <<= 1) {
        int u = (t >= off) ? s[t - off] : 0;
        __syncthreads(); s[t] += u; __syncthreads();
    }
    if (t < 196) bsum[t] = s[t] - v;
}

__global__ __launch_bounds__(256) void scan3_kernel(int* __restrict__ cursor,
                                                    const int* __restrict__ bsum) {
    int i = blockIdx.x * 256 + threadIdx.x;
    cursor[i] += bsum[blockIdx.x];
}

__global__ __launch_bounds__(256) void scatter_kernel(const int* __restrict__ eidx,
                                                      int* __restrict__ cursor,
                                                      int* __restrict__ sorted) {
    int e = blockIdx.x * 256 + threadIdx.x;
    if (e < NE) {
        int pos = atomicAdd(&cursor[eidx[e]], 1);
        sorted[pos] = e;
    }
}

// ---- edge-TP weights: f16, pre-scaled, MFMA 16x16x32 B-frag layout,
//      tt-CONSECUTIVE: id = ((tt*6 + s)*64 + lane)*8 + j ----
__global__ __launch_bounds__(256) void wprep_edge_kernel(
    const float* __restrict__ W1, const float* __restrict__ W2,
    const float* __restrict__ W3, const float* __restrict__ W4,
    unsigned short* __restrict__ Wh)
{
    int id = blockIdx.x * 256 + threadIdx.x;   // 73728 total
    if (id >= 73728) return;
    int j = id & 7, l = (id >> 3) & 63, st = id >> 9;  // st = tt*6+s
    int tt = st / 6, s = st % 6;
    int k = 32 * tt + 8 * (l >> 4) + j;
    float w;
    if (s < 4) {
        int c = s * 16 + (l & 15);
        if (k < 512) { int a = k >> 3, b = k & 7; w = W1[(a*8+b)*64 + c] * SC; }
        else { int k2 = k - 512; int a = k2 >> 3, b = k2 & 7; w = W2[(a*8+b)*64 + c] * (R2*SC); }
    } else {
        int c = (s - 4) * 16 + (l & 15);
        if (k < 512) { int a = k >> 3, b = k & 7; w = W3[(a*8+b)*32 + c] * SC; }
        else { int k2 = k - 512; int a = k2 >> 3, b = k2 & 7; w = W4[(a*8+b)*32 + c] * (R4*SC); }
    }
    Wh[id] = f16bits(w);
}

// ---- Wc = Wm @ Wu_bot (fp32), bc = bm @ Wu_bot ----
__global__ __launch_bounds__(256) void wcomp_kernel(
    const float* __restrict__ Wm, const float* __restrict__ bm,
    const float* __restrict__ Wu, float* __restrict__ Wc, float* __restrict__ bc)
{
    int id = blockIdx.x * 256 + threadIdx.x;
    if (id < 160 * 160) {
        int k = id / 160, c = id % 160;
        float s = 0.0f;
        for (int h = 0; h < 160; ++h) s = fmaf(Wm[k*160 + h], Wu[(160 + h)*160 + c], s);
        Wc[id] = s;
    }
    if (id < 160) {
        float s = 0.0f;
        for (int h = 0; h < 160; ++h) s = fmaf(bm[h], Wu[(160 + h)*160 + id], s);
        bc[id] = s;
    }
}

// ---- node-GEMM weights (f16): [Wu_top(160); Wc permuted to T's i-major layout] ----
__global__ __launch_bounds__(256) void wprep_node_kernel(
    const float* __restrict__ Wu, const float* __restrict__ Wc,
    unsigned short* __restrict__ Wn)
{
    int id = blockIdx.x * 256 + threadIdx.x;   // 51200 total
    if (id >= 51200) return;
    int j = id & 7, l = (id >> 3) & 63, tn = id >> 9;  // tn = n16*10 + tk
    int tk = tn % 10, n16 = tn / 10;
    int c = n16 * 16 + (l & 15);
    int k = 32 * tk + 8 * (l >> 4) + j;
    float w;
    if (k < 160) {
        w = Wu[k * 160 + c];
    } else {
        int tcol = k - 160;  // T col: [0,64)=s ; 64+i*32+cc (i-major v)
        int orig = (tcol < 64) ? tcol : 64 + ((tcol - 64) & 31) * 3 + ((tcol - 64) >> 5);
        w = Wc[orig * 160 + c];
    }
    Wn[id] = f16bits(w);
}

// ---- per-edge TP via f16 MFMA, dest-sorted edges (R13 structure).
//      Weights staged per-block into 2-deep LDS dbuf via global_load_lds;
//      A-source x-values PRELOADED to registers (40 per lane, one-time) so
//      the K-loop has zero A-side LDS reads; K-loop fully unrolled. ----
template<int UXB>
__global__ __launch_bounds__(256, 3) void edge_kernel(
    const float* __restrict__ x, const unsigned short* __restrict__ xb,
    const int* __restrict__ eidx, const float* __restrict__ ea,
    const unsigned short* __restrict__ Wh,
    const int* __restrict__ sorted, float* __restrict__ T)
{
    // xls 22016 B | els 4864 B | wbuf 2x6144 B  = 39168 B (4 blocks/CU)
    // epilogue accw[32][161] f32 (20608 B) overlays xls
    __shared__ __align__(16) char smem[64*XST*2 + 64*EST*2 + 2*3072*2];
    __shared__ int rowls[64];
    __shared__ int colls[64];
    __shared__ int sels[64];

    unsigned short* xls  = (unsigned short*)smem;                        // [64][XST] f16
    unsigned short* els  = (unsigned short*)(smem + 64*XST*2);           // [64][EST] f16
    unsigned short* wbuf = (unsigned short*)(smem + 64*XST*2 + 64*EST*2); // [2][3072] f16

    const int t = threadIdx.x;
    const int base = blockIdx.x * 64;

    if (t < 64) {
        const int se = sorted[base + t];
        sels[t] = se;
        rowls[t] = eidx[se];
        colls[t] = eidx[NE + se];
    }
    __syncthreads();

    if (UXB) {
        for (int j = t; j < 64 * 40; j += 256) {
            int m = j / 40, q = j - m * 40;
            const u16x4 v = *reinterpret_cast<const u16x4*>(xb + (size_t)colls[m] * DN + q * 4);
            *reinterpret_cast<u16x4*>(&xls[m*XST + q*4]) = v;
        }
    } else {
        for (int j = t; j < 64 * 40; j += 256) {
            int m = j / 40, q = j - m * 40;
            const float4 v = *reinterpret_cast<const float4*>(x + (size_t)colls[m] * DN + q * 4);
            u16x4 p; p[0] = f16bits(v.x); p[1] = f16bits(v.y); p[2] = f16bits(v.z); p[3] = f16bits(v.w);
            *reinterpret_cast<u16x4*>(&xls[m*XST + q*4]) = p;
        }
    }
    // e staging with transpose of the vector part
    for (int j = t; j < 64 * 8; j += 256) {
        int m = j >> 3, q = j & 7;
        const float4 v = *reinterpret_cast<const float4*>(ea + (size_t)sels[m] * DE + q * 4);
        #pragma unroll
        for (int z = 0; z < 4; ++z) {
            int p = q * 4 + z;
            float val = (z == 0) ? v.x : (z == 1) ? v.y : (z == 2) ? v.z : v.w;
            int dst = (p < 8) ? p : 8 + ((p - 8) % 3) * 8 + (p - 8) / 3;
            els[m*EST + dst] = f16bits(val);
        }
    }

    const int lane = t & 63;
    const int wv = t >> 6;        // 0..3
    const int r = lane & 15;      // A row / B col / C col
    const int g = lane >> 4;      // k-group
    const int er = wv * 16 + r;   // edge owning this lane's A row

    // stage weights of k-tile tt into wbuf[buf]: wave wv loads chunks wv (+ wv+4)
    #define STAGE_W(buf, tt)                                                       \
        do {                                                                       \
            const unsigned short* wsrc = Wh + (size_t)(tt) * 3072;                 \
            unsigned short* wdst = wbuf + (buf) * 3072;                            \
            load_lds16(wsrc + wv * 512 + lane * 8, wdst + wv * 512);               \
            if (wv < 2)                                                            \
                load_lds16(wsrc + (wv + 4) * 512 + lane * 8, wdst + (wv + 4) * 512); \
        } while (0)

    STAGE_W(0, 0);   // prologue (drains at the staging barrier)

    __syncthreads();  // x/e staging + weight tile 0 complete

    // ---- one-time preload: edge attrs + this lane's 40 x-values -> registers ----
    f16x2 es2[4], ev2[3][4];
    #pragma unroll
    for (int p = 0; p < 4; ++p) {
        es2[p] = *reinterpret_cast<const f16x2*>(&els[er*EST + 2*p]);
        #pragma unroll
        for (int i = 0; i < 3; ++i)
            ev2[i][p] = *reinterpret_cast<const f16x2*>(&els[er*EST + 8 + i*8 + 2*p]);
    }
    _Float16 xa1[16];
    #pragma unroll
    for (int tt = 0; tt < 16; ++tt)
        xa1[tt] = *reinterpret_cast<const _Float16*>(&xls[er*XST + 4*tt + g]);
    _Float16 xv0[8], xv1[8], xv2[8];
    #pragma unroll
    for (int u = 0; u < 8; ++u) {
        const int bidx = er*XST + 64 + (4*u + g)*3;
        xv0[u] = *reinterpret_cast<const _Float16*>(&xls[bidx + 0]);
        xv1[u] = *reinterpret_cast<const _Float16*>(&xls[bidx + 1]);
        xv2[u] = *reinterpret_cast<const _Float16*>(&xls[bidx + 2]);
    }

    f32x4 accS[4], accV[3][2];
    #pragma unroll
    for (int n = 0; n < 4; ++n) accS[n] = (f32x4){0.f, 0.f, 0.f, 0.f};
    #pragma unroll
    for (int i = 0; i < 3; ++i)
        #pragma unroll
        for (int n = 0; n < 2; ++n) accV[i][n] = (f32x4){0.f, 0.f, 0.f, 0.f};

#define KSTEP_HEAD(tt)                                                             \
        if (tt) __syncthreads();                                                   \
        if ((tt) + 1 < 24) STAGE_W(((tt) + 1) & 1, (tt) + 1);                      \
        const unsigned short* wb = wbuf + ((tt) & 1) * 3072 + lane * 8;            \
        f16x8 B[6];                                                                \
        _Pragma("unroll")                                                          \
        for (int n = 0; n < 6; ++n)                                                \
            B[n] = *reinterpret_cast<const f16x8*>(wb + n * 512);

#define EDGE_MFMAS()                                                               \
        accS[0] = __builtin_amdgcn_mfma_f32_16x16x32_f16(aS.v,  B[0], accS[0],0,0,0); \
        accS[1] = __builtin_amdgcn_mfma_f32_16x16x32_f16(aS.v,  B[1], accS[1],0,0,0); \
        accS[2] = __builtin_amdgcn_mfma_f32_16x16x32_f16(aS.v,  B[2], accS[2],0,0,0); \
        accS[3] = __builtin_amdgcn_mfma_f32_16x16x32_f16(aS.v,  B[3], accS[3],0,0,0); \
        accV[0][0] = __builtin_amdgcn_mfma_f32_16x16x32_f16(aV0.v, B[4], accV[0][0],0,0,0); \
        accV[0][1] = __builtin_amdgcn_mfma_f32_16x16x32_f16(aV0.v, B[5], accV[0][1],0,0,0); \
        accV[1][0] = __builtin_amdgcn_mfma_f32_16x16x32_f16(aV1.v, B[4], accV[1][0],0,0,0); \
        accV[1][1] = __builtin_amdgcn_mfma_f32_16x16x32_f16(aV1.v, B[5], accV[1][1],0,0,0); \
        accV[2][0] = __builtin_amdgcn_mfma_f32_16x16x32_f16(aV2.v, B[4], accV[2][0],0,0,0); \
        accV[2][1] = __builtin_amdgcn_mfma_f32_16x16x32_f16(aV2.v, B[5], accV[2][1],0,0,0);

    // ---- phase 1: k<512 (xs x e outer products), tiles 0..15, unrolled ----
    #pragma unroll
    for (int tt = 0; tt < 16; ++tt) {
        KSTEP_HEAD(tt);
        const f16x2 xa2 = (f16x2){xa1[tt], xa1[tt]};
        AF aS, aV0, aV1, aV2;
        #pragma unroll
        for (int p = 0; p < 4; ++p) {
            aS.p[p]  = xa2 * es2[p];
            aV0.p[p] = xa2 * ev2[0][p];
            aV1.p[p] = xa2 * ev2[1][p];
            aV2.p[p] = xa2 * ev2[2][p];
        }
        EDGE_MFMAS();
    }

    // ---- phase 2: k>=512 (xv-based products), tiles 16..23, unrolled ----
    #pragma unroll
    for (int u = 0; u < 8; ++u) {
        KSTEP_HEAD(16 + u);
        const f16x2 x02 = (f16x2){xv0[u], xv0[u]};
        const f16x2 x12 = (f16x2){xv1[u], xv1[u]};
        const f16x2 x22 = (f16x2){xv2[u], xv2[u]};
        AF aS, aV0, aV1, aV2;
        #pragma unroll
        for (int p = 0; p < 4; ++p) {
            f16x2 d = x02 * ev2[0][p];
            d += x12 * ev2[1][p];
            d += x22 * ev2[2][p];
            aS.p[p]  = d;                   // z2 dot (r2 folded in W)
            aV0.p[p] = x02 * es2[p];        // z4 (r4 folded in W)
            aV1.p[p] = x12 * es2[p];
            aV2.p[p] = x22 * es2[p];
        }
        EDGE_MFMAS();
    }
#undef KSTEP_HEAD
#undef EDGE_MFMAS
#undef STAGE_W

    __syncthreads();   // done with staging; reuse smem for acc (2 chunks of 32)
    float* accw = (float*)smem;  // [32][161]

    #pragma unroll
    for (int half = 0; half < 2; ++half) {
        if ((wv >> 1) == half) {
            const int lbase = (wv & 1) * 16 + g * 4;
            #pragma unroll
            for (int reg = 0; reg < 4; ++reg) {
                const int lrow = lbase + reg;
                #pragma unroll
                for (int n = 0; n < 4; ++n)
                    accw[lrow*161 + n*16 + r] = accS[n][reg];
                #pragma unroll
                for (int i = 0; i < 3; ++i)
                    #pragma unroll
                    for (int n = 0; n < 2; ++n)
                        accw[lrow*161 + 64 + i*32 + n*16 + r] = accV[i][n][reg];  // i-major
            }
        }
        __syncthreads();

        if (t < DN) {
            const int col = t;
            const int ebase = half * 32;
            float s = 0.0f;
            int rstart = 0;
            for (int e = 0; e < 32; ++e) {
                s += accw[e*161 + col];
                const int ge = ebase + e;
                if (e == 31 || rowls[ge] != rowls[ge + 1]) {
                    float* dst = T + (size_t)rowls[ge] * DN + col;
                    if (rstart == 0 || e == 31) atomicAdd(dst, s);  // chunk-boundary run
                    else *dst = s;                                   // interior: exclusive
                    s = 0.0f; rstart = e + 1;
                }
            }
        }
        __syncthreads();
    }
}

// ---- node update: out = x + [f16(x), f16(T)] @ Wn + bu + deg*bc ----
template<int UXB>
__global__ __launch_bounds__(256) void node_kernel(
    const float* __restrict__ x, const unsigned short* __restrict__ xb,
    float* __restrict__ T, const int* __restrict__ cnt,
    const unsigned short* __restrict__ Wn,
    const float* __restrict__ bu, const float* __restrict__ bc)
{
    __shared__ __align__(16) unsigned short A[64][328];  // 160 x | 160 T (f16)
    const int t = threadIdx.x;
    const int nb = blockIdx.x * 64;

    if (UXB) {
        for (int j = t; j < 64 * 40; j += 256) {   // x-part straight f16 copy
            int m = j / 40, q = j - m * 40;
            int row = nb + m; if (row >= NN) row = NN - 1;
            const u16x4 v = *reinterpret_cast<const u16x4*>(xb + (size_t)row * DN + q * 4);
            *reinterpret_cast<u16x4*>(&A[m][q*4]) = v;
        }
    } else {
        for (int j = t; j < 64 * 40; j += 256) {
            int m = j / 40, q = j - m * 40;
            int row = nb + m; if (row >= NN) row = NN - 1;
            const float4 v = *reinterpret_cast<const float4*>(x + (size_t)row * DN + q * 4);
            u16x4 p; p[0] = f16bits(v.x); p[1] = f16bits(v.y); p[2] = f16bits(v.z); p[3] = f16bits(v.w);
            *reinterpret_cast<u16x4*>(&A[m][q*4]) = p;
        }
    }
    for (int j = t; j < 64 * 40; j += 256) {       // T-part with cvt
        int m = j / 40, q = j - m * 40;
        int row = nb + m; if (row >= NN) row = NN - 1;
        const float4 v = *reinterpret_cast<const float4*>(T + (size_t)row * DN + q * 4);
        u16x4 p; p[0] = f16bits(v.x); p[1] = f16bits(v.y); p[2] = f16bits(v.z); p[3] = f16bits(v.w);
        *reinterpret_cast<u16x4*>(&A[m][160 + q*4]) = p;
    }
    __syncthreads();

    const int lane = t & 63;
    const int wv = t >> 6;
    const int r = lane & 15, g = lane >> 4;
    const int er = wv * 16 + r;

    f32x4 acc[10];
    #pragma unroll
    for (int n = 0; n < 10; ++n) acc[n] = (f32x4){0.f, 0.f, 0.f, 0.f};

    for (int tk = 0; tk < 10; ++tk) {
        const f16x8 a = *reinterpret_cast<const f16x8*>(&A[er][32 * tk + 8 * g]);
        #pragma unroll
        for (int n = 0; n < 10; ++n) {
            const f16x8 b = *reinterpret_cast<const f16x8*>(Wn + ((size_t)(n * 10 + tk) * 64 + lane) * 8);
            acc[n] = __builtin_amdgcn_mfma_f32_16x16x32_f16(a, b, acc[n], 0, 0, 0);
        }
    }

    #pragma unroll
    for (int reg = 0; reg < 4; ++reg) {
        const int nrow = nb + wv * 16 + g * 4 + reg;
        if (nrow < NN) {
            const float dg = (float)cnt[nrow];
            #pragma unroll
            for (int n = 0; n < 10; ++n) {
                const int c = n * 16 + r;
                T[(size_t)nrow * DN + c] =
                    acc[n][reg] + x[(size_t)nrow * DN + c] + bu[c] + dg * bc[c];
            }
        }
    }
}

extern "C" void kernel_launch(void* const* d_in, const int* in_sizes, int n_in,
                              void* d_out, int out_size, void* d_ws, size_t ws_size,
                              hipStream_t stream) {
    const float* xf   = (const float*)d_in[0];
    const int*   eidx = (const int*)d_in[1];
    const float* ea   = (const float*)d_in[2];
    const float* W1 = (const float*)d_in[4];
    const float* W2 = (const float*)d_in[5];
    const float* W3 = (const float*)d_in[6];
    const float* W4 = (const float*)d_in[7];
    const float* Wm = (const float*)d_in[8];
    const float* bm = (const float*)d_in[9];
    const float* Wu = (const float*)d_in[10];
    const float* bu = (const float*)d_in[11];

    float* out = (float*)d_out;   // doubles as tp-accumulator T

    char* ws = (char*)d_ws;
    int*            cnt    = (int*)ws;                              // 200 KB
    int*            cursor = (int*)(ws + (256 << 10));              // 200 KB
    int*            sorted = (int*)(ws + (512 << 10));              // 3.2 MB
    int*            bsum   = (int*)(ws + (3968 << 10));             // 1 KB
    unsigned short* Wh     = (unsigned short*)(ws + (4096 << 10));  // 144 KB f16 edge W
    float*          Wc     = (float*)(ws + (4352 << 10));           // 100 KB
    float*          bc     = (float*)(ws + (4480 << 10));           // 640 B
    unsigned short* Wn     = (unsigned short*)(ws + (4608 << 10));  // 100 KB f16 node W
    unsigned short* xb     = (unsigned short*)(ws + (4864 << 10));  // 16 MB f16 x

    const bool uxb = ws_size >= ((size_t)(4864 + 16000) << 10);

    wcomp_kernel<<<100, 256, 0, stream>>>(Wm, bm, Wu, Wc, bc);
    wprep_node_kernel<<<200, 256, 0, stream>>>(Wu, Wc, Wn);
    wprep_edge_kernel<<<288, 256, 0, stream>>>(W1, W2, W3, W4, Wh);
    if (uxb) xprep_kernel<<<(NN * DN / 4 + 255) / 256, 256, 0, stream>>>(xf, xb);
    zero_kernel<<<(NN * DN + 255) / 256, 256, 0, stream>>>(out, cnt);
    hist_kernel<<<NE / 256, 256, 0, stream>>>(eidx, cnt);
    scan1_kernel<<<NP / 256, 256, 0, stream>>>(cnt, cursor, bsum);
    scan2_kernel<<<1, 256, 0, stream>>>(bsum);
    scan3_kernel<<<NP / 256, 256, 0, stream>>>(cursor, bsum);
    scatter_kernel<<<NE / 256, 256, 0, stream>>>(eidx, cursor, sorted);
    if (uxb) {
        edge_kernel<1><<<NE / 64, 256, 0, stream>>>(xf, xb, eidx, ea, Wh, sorted, out);
        node_kernel<1><<<(NN + 63) / 64, 256, 0, stream>>>(xf, xb, out, cnt, Wn, bu, bc);
    } else {
        edge_kernel<0><<<NE / 64, 256, 0, stream>>>(xf, xb, eidx, ea, Wh, sorted, out);
        node_kernel<0><<<(NN + 63) / 64, 256, 0, stream>>>(xf, xb, out, cnt, Wn, bu, bc);
    }
}

// Round 16
// 457.224 us; speedup vs baseline: 1.2194x; 1.1477x over previous
//
#include <hip/hip_runtime.h>
#include <hip/hip_bf16.h>

#define NN 50000
#define NE 800000
#define DN 160
#define DE 32
#define NP 50176              /* NN padded to 196*256 */

typedef __attribute__((ext_vector_type(2))) _Float16 f16x2;
typedef __attribute__((ext_vector_type(8))) _Float16 f16x8;
typedef __attribute__((ext_vector_type(4))) float f32x4;
typedef __attribute__((ext_vector_type(4))) unsigned short u16x4;

#define R2 0.81649658092772603f   /* sqrt(2/3): W2 rel scale */
#define R4 1.41421356237309515f   /* sqrt(2):   W4 rel scale */
#define SC (1.0f/32.0f)           /* global scale folded into weights */

#define XST 172                   /* xls row stride (u16) */
#define EST 38                    /* els row stride (u16) */

/* prep1 grid ranges */
#define XPREP_B 7813              /* 2,000,000 float4 of x */
#define WEDGE_B 288               /* 73728 edge-W elems */
#define WCOMP_B 100               /* 25600 Wc/bc elems */
#define ZERO_B  7813              /* 2,000,000 float4 of T + NP cnt */

union AF { f16x2 p[4]; f16x8 v; };

__device__ __forceinline__ unsigned short f16bits(float f) {
    union { _Float16 h; unsigned short s; } u;
    u.h = (_Float16)f;
    return u.s;
}

// async global->LDS, 16B per lane; dst is wave-uniform base (HW adds lane*16)
__device__ __forceinline__ void load_lds16(const void* g, void* l) {
    __builtin_amdgcn_global_load_lds(
        (const __attribute__((address_space(1))) unsigned int*)g,
        (__attribute__((address_space(3))) unsigned int*)l, 16, 0, 0);
}

// ---- fused prep1: {x->f16 copy | edge-W prep | Wc=Wm@Wu_bot | zero T,cnt} ----
// all four pieces are mutually independent; selected by blockIdx range.
template<int UXB>
__global__ __launch_bounds__(256) void prep1_kernel(
    const float* __restrict__ x,
    const float* __restrict__ W1, const float* __restrict__ W2,
    const float* __restrict__ W3, const float* __restrict__ W4,
    const float* __restrict__ Wm, const float* __restrict__ bm,
    const float* __restrict__ Wu,
    unsigned short* __restrict__ Wh, float* __restrict__ Wc,
    float* __restrict__ bc, unsigned short* __restrict__ xb,
    float* __restrict__ T, int* __restrict__ cnt)
{
    const int b = blockIdx.x, t = threadIdx.x;
    if (b < XPREP_B) {
        if (UXB) {
            int i = b * 256 + t;
            if (i < NN * DN / 4) {
                const float4 v = reinterpret_cast<const float4*>(x)[i];
                u16x4 p; p[0] = f16bits(v.x); p[1] = f16bits(v.y);
                p[2] = f16bits(v.z); p[3] = f16bits(v.w);
                reinterpret_cast<u16x4*>(xb)[i] = p;
            }
        }
    } else if (b < XPREP_B + WEDGE_B) {
        // edge-TP weights: f16, pre-scaled, MFMA 16x16x32 B-frag layout,
        // tt-CONSECUTIVE: id = ((tt*6 + s)*64 + lane)*8 + j
        int id = (b - XPREP_B) * 256 + t;
        if (id < 73728) {
            int j = id & 7, l = (id >> 3) & 63, st = id >> 9;  // st = tt*6+s
            int tt = st / 6, s = st % 6;
            int k = 32 * tt + 8 * (l >> 4) + j;
            float w;
            if (s < 4) {
                int c = s * 16 + (l & 15);
                if (k < 512) { int a = k >> 3, bq = k & 7; w = W1[(a*8+bq)*64 + c] * SC; }
                else { int k2 = k - 512; int a = k2 >> 3, bq = k2 & 7; w = W2[(a*8+bq)*64 + c] * (R2*SC); }
            } else {
                int c = (s - 4) * 16 + (l & 15);
                if (k < 512) { int a = k >> 3, bq = k & 7; w = W3[(a*8+bq)*32 + c] * SC; }
                else { int k2 = k - 512; int a = k2 >> 3, bq = k2 & 7; w = W4[(a*8+bq)*32 + c] * (R4*SC); }
            }
            Wh[id] = f16bits(w);
        }
    } else if (b < XPREP_B + WEDGE_B + WCOMP_B) {
        int id = (b - XPREP_B - WEDGE_B) * 256 + t;
        if (id < 160 * 160) {
            int k = id / 160, c = id % 160;
            float s = 0.0f;
            for (int h = 0; h < 160; ++h) s = fmaf(Wm[k*160 + h], Wu[(160 + h)*160 + c], s);
            Wc[id] = s;
        }
        if (id < 160) {
            float s = 0.0f;
            for (int h = 0; h < 160; ++h) s = fmaf(bm[h], Wu[(160 + h)*160 + id], s);
            bc[id] = s;
        }
    } else {
        int i = (b - XPREP_B - WEDGE_B - WCOMP_B) * 256 + t;
        if (i < NN * DN / 4)
            reinterpret_cast<float4*>(T)[i] = (float4){0.f, 0.f, 0.f, 0.f};
        if (i < NP) cnt[i] = 0;
    }
}

// ---- fused prep2: {node-GEMM weight prep (needs Wc) | histogram (needs cnt=0)} ----
__global__ __launch_bounds__(256) void prep2_kernel(
    const float* __restrict__ Wu, const float* __restrict__ Wc,
    unsigned short* __restrict__ Wn,
    const int* __restrict__ eidx, int* __restrict__ cnt)
{
    const int b = blockIdx.x, t = threadIdx.x;
    if (b < 200) {
        int id = b * 256 + t;   // 51200 total
        if (id < 51200) {
            int j = id & 7, l = (id >> 3) & 63, tn = id >> 9;  // tn = n16*10 + tk
            int tk = tn % 10, n16 = tn / 10;
            int c = n16 * 16 + (l & 15);
            int k = 32 * tk + 8 * (l >> 4) + j;
            float w;
            if (k < 160) {
                w = Wu[k * 160 + c];
            } else {
                int tcol = k - 160;  // T col: [0,64)=s ; 64+i*32+cc (i-major v)
                int orig = (tcol < 64) ? tcol : 64 + ((tcol - 64) & 31) * 3 + ((tcol - 64) >> 5);
                w = Wc[orig * 160 + c];
            }
            Wn[id] = f16bits(w);
        }
    } else {
        int e = (b - 200) * 256 + t;
        if (e < NE) atomicAdd(&cnt[eidx[e]], 1);
    }
}

__global__ __launch_bounds__(256) void scan1_kernel(const int* __restrict__ cnt,
                                                    int* __restrict__ cursor,
                                                    int* __restrict__ bsum) {
    __shared__ int s[256];
    const int t = threadIdx.x;
    const int i = blockIdx.x * 256 + t;
    const int v = cnt[i];
    s[t] = v; __syncthreads();
    for (int off = 1; off < 256; off <<= 1) {
        int u = (t >= off) ? s[t - off] : 0;
        __syncthreads(); s[t] += u; __syncthreads();
    }
    cursor[i] = s[t] - v;
    if (t == 255) bsum[blockIdx.x] = s[255];
}

__global__ __launch_bounds__(256) void scan2_kernel(int* __restrict__ bsum) {
    __shared__ int s[256];
    const int t = threadIdx.x;
    const int v = (t < 196) ? bsum[t] : 0;
    s[t] = v; __syncthreads();
    for (int off = 1; off < 256; off <<= 1) {
        int u = (t >= off) ? s[t - off] : 0;
        __syncthreads(); s[t] += u; __syncthreads();
    }
    if (t < 196) bsum[t] = s[t] - v;
}

__global__ __launch_bounds__(256) void scan3_kernel(int* __restrict__ cursor,
                                                    const int* __restrict__ bsum) {
    int i = blockIdx.x * 256 + threadIdx.x;
    cursor[i] += bsum[blockIdx.x];
}

__global__ __launch_bounds__(256) void scatter_kernel(const int* __restrict__ eidx,
                                                      int* __restrict__ cursor,
                                                      int* __restrict__ sorted) {
    int e = blockIdx.x * 256 + threadIdx.x;
    if (e < NE) {
        int pos = atomicAdd(&cursor[eidx[e]], 1);
        sorted[pos] = e;
    }
}

// A-fragment formation for k-tile tt (uniform branch)
__device__ __forceinline__ void makeA(int tt, int g, int er,
    const unsigned short* __restrict__ xls,
    const f16x2 es2[4], const f16x2 ev2[3][4],
    AF& aS, AF& aV0, AF& aV1, AF& aV2)
{
    if (tt < 16) {
        const _Float16 xa = *reinterpret_cast<const _Float16*>(&xls[er*XST + 4*tt + g]);
        const f16x2 xa2 = (f16x2){xa, xa};
        #pragma unroll
        for (int p = 0; p < 4; ++p) {
            aS.p[p]  = xa2 * es2[p];
            aV0.p[p] = xa2 * ev2[0][p];
            aV1.p[p] = xa2 * ev2[1][p];
            aV2.p[p] = xa2 * ev2[2][p];
        }
    } else {
        const int a = 4 * (tt - 16) + g;
        const _Float16 x0 = *reinterpret_cast<const _Float16*>(&xls[er*XST + 64 + a*3 + 0]);
        const _Float16 x1 = *reinterpret_cast<const _Float16*>(&xls[er*XST + 64 + a*3 + 1]);
        const _Float16 x2 = *reinterpret_cast<const _Float16*>(&xls[er*XST + 64 + a*3 + 2]);
        const f16x2 x02 = (f16x2){x0, x0};
        const f16x2 x12 = (f16x2){x1, x1};
        const f16x2 x22 = (f16x2){x2, x2};
        #pragma unroll
        for (int p = 0; p < 4; ++p) {
            f16x2 d = x02 * ev2[0][p];
            d += x12 * ev2[1][p];
            d += x22 * ev2[2][p];
            aS.p[p]  = d;                   // z2 dot (r2 folded in W)
            aV0.p[p] = x02 * es2[p];        // z4 (r4 folded in W)
            aV1.p[p] = x12 * es2[p];
            aV2.p[p] = x22 * es2[p];
        }
    }
}

// ---- per-edge TP via f16 MFMA, dest-sorted edges (R13 champion config).
//      Weights staged per-block into 2-deep LDS dbuf via global_load_lds;
//      one barrier per k-tile; plain-store interior runs, atomic boundaries. ----
template<int UXB>
__global__ __launch_bounds__(256, 3) void edge_kernel(
    const float* __restrict__ x, const unsigned short* __restrict__ xb,
    const int* __restrict__ eidx, const float* __restrict__ ea,
    const unsigned short* __restrict__ Wh,
    const int* __restrict__ sorted, float* __restrict__ T)
{
    // xls 22016 B | els 4864 B | wbuf 2x6144 B  = 39168 B (4 blocks/CU)
    // epilogue accw[32][161] f32 (20608 B) overlays xls
    __shared__ __align__(16) char smem[64*XST*2 + 64*EST*2 + 2*3072*2];
    __shared__ int rowls[64];
    __shared__ int colls[64];
    __shared__ int sels[64];

    unsigned short* xls  = (unsigned short*)smem;                        // [64][XST] f16
    unsigned short* els  = (unsigned short*)(smem + 64*XST*2);           // [64][EST] f16
    unsigned short* wbuf = (unsigned short*)(smem + 64*XST*2 + 64*EST*2); // [2][3072] f16

    const int t = threadIdx.x;
    const int base = blockIdx.x * 64;

    if (t < 64) {
        const int se = sorted[base + t];
        sels[t] = se;
        rowls[t] = eidx[se];
        colls[t] = eidx[NE + se];
    }
    __syncthreads();

    if (UXB) {
        for (int j = t; j < 64 * 40; j += 256) {
            int m = j / 40, q = j - m * 40;
            const u16x4 v = *reinterpret_cast<const u16x4*>(xb + (size_t)colls[m] * DN + q * 4);
            *reinterpret_cast<u16x4*>(&xls[m*XST + q*4]) = v;
        }
    } else {
        for (int j = t; j < 64 * 40; j += 256) {
            int m = j / 40, q = j - m * 40;
            const float4 v = *reinterpret_cast<const float4*>(x + (size_t)colls[m] * DN + q * 4);
            u16x4 p; p[0] = f16bits(v.x); p[1] = f16bits(v.y); p[2] = f16bits(v.z); p[3] = f16bits(v.w);
            *reinterpret_cast<u16x4*>(&xls[m*XST + q*4]) = p;
        }
    }
    // e staging with transpose of the vector part
    for (int j = t; j < 64 * 8; j += 256) {
        int m = j >> 3, q = j & 7;
        const float4 v = *reinterpret_cast<const float4*>(ea + (size_t)sels[m] * DE + q * 4);
        #pragma unroll
        for (int z = 0; z < 4; ++z) {
            int p = q * 4 + z;
            float val = (z == 0) ? v.x : (z == 1) ? v.y : (z == 2) ? v.z : v.w;
            int dst = (p < 8) ? p : 8 + ((p - 8) % 3) * 8 + (p - 8) / 3;
            els[m*EST + dst] = f16bits(val);
        }
    }

    const int lane = t & 63;
    const int wv = t >> 6;        // 0..3
    const int r = lane & 15;      // A row / B col / C col
    const int g = lane >> 4;      // k-group
    const int er = wv * 16 + r;   // edge owning this lane's A row

    // stage weights of k-tile tt into wbuf[buf]: wave wv loads chunks wv (+ wv+4)
    #define STAGE_W(buf, tt)                                                       \
        do {                                                                       \
            const unsigned short* wsrc = Wh + (size_t)(tt) * 3072;                 \
            unsigned short* wdst = wbuf + (buf) * 3072;                            \
            load_lds16(wsrc + wv * 512 + lane * 8, wdst + wv * 512);               \
            if (wv < 2)                                                            \
                load_lds16(wsrc + (wv + 4) * 512 + lane * 8, wdst + (wv + 4) * 512); \
        } while (0)

    STAGE_W(0, 0);   // prologue (drains at the staging barrier)

    __syncthreads();  // x/e staging + weight tile 0 complete

    f16x2 es2[4], ev2[3][4];
    #pragma unroll
    for (int p = 0; p < 4; ++p) {
        es2[p] = *reinterpret_cast<const f16x2*>(&els[er*EST + 2*p]);
        #pragma unroll
        for (int i = 0; i < 3; ++i)
            ev2[i][p] = *reinterpret_cast<const f16x2*>(&els[er*EST + 8 + i*8 + 2*p]);
    }

    f32x4 accS[4], accV[3][2];
    #pragma unroll
    for (int n = 0; n < 4; ++n) accS[n] = (f32x4){0.f, 0.f, 0.f, 0.f};
    #pragma unroll
    for (int i = 0; i < 3; ++i)
        #pragma unroll
        for (int n = 0; n < 2; ++n) accV[i][n] = (f32x4){0.f, 0.f, 0.f, 0.f};

    for (int tt = 0; tt < 24; ++tt) {
        const int cur = tt & 1;
        if (tt) __syncthreads();   // tile tt's loads landed; prev readers done
        if (tt + 1 < 24) STAGE_W(cur ^ 1, tt + 1);   // fly during this compute

        const unsigned short* wb = wbuf + cur * 3072 + lane * 8;
        f16x8 B[6];
        #pragma unroll
        for (int n = 0; n < 6; ++n)
            B[n] = *reinterpret_cast<const f16x8*>(wb + n * 512);  // ds_read_b128

        AF aS, aV0, aV1, aV2;
        makeA(tt, g, er, xls, es2, ev2, aS, aV0, aV1, aV2);

        accS[0] = __builtin_amdgcn_mfma_f32_16x16x32_f16(aS.v,  B[0], accS[0],0,0,0);
        accS[1] = __builtin_amdgcn_mfma_f32_16x16x32_f16(aS.v,  B[1], accS[1],0,0,0);
        accS[2] = __builtin_amdgcn_mfma_f32_16x16x32_f16(aS.v,  B[2], accS[2],0,0,0);
        accS[3] = __builtin_amdgcn_mfma_f32_16x16x32_f16(aS.v,  B[3], accS[3],0,0,0);
        accV[0][0] = __builtin_amdgcn_mfma_f32_16x16x32_f16(aV0.v, B[4], accV[0][0],0,0,0);
        accV[0][1] = __builtin_amdgcn_mfma_f32_16x16x32_f16(aV0.v, B[5], accV[0][1],0,0,0);
        accV[1][0] = __builtin_amdgcn_mfma_f32_16x16x32_f16(aV1.v, B[4], accV[1][0],0,0,0);
        accV[1][1] = __builtin_amdgcn_mfma_f32_16x16x32_f16(aV1.v, B[5], accV[1][1],0,0,0);
        accV[2][0] = __builtin_amdgcn_mfma_f32_16x16x32_f16(aV2.v, B[4], accV[2][0],0,0,0);
        accV[2][1] = __builtin_amdgcn_mfma_f32_16x16x32_f16(aV2.v, B[5], accV[2][1],0,0,0);
    }
    #undef STAGE_W

    __syncthreads();   // done with staging; reuse smem for acc (2 chunks of 32)
    float* accw = (float*)smem;  // [32][161]

    #pragma unroll
    for (int half = 0; half < 2; ++half) {
        if ((wv >> 1) == half) {
            const int lbase = (wv & 1) * 16 + g * 4;
            #pragma unroll
            for (int reg = 0; reg < 4; ++reg) {
                const int lrow = lbase + reg;
                #pragma unroll
                for (int n = 0; n < 4; ++n)
                    accw[lrow*161 + n*16 + r] = accS[n][reg];
                #pragma unroll
                for (int i = 0; i < 3; ++i)
                    #pragma unroll
                    for (int n = 0; n < 2; ++n)
                        accw[lrow*161 + 64 + i*32 + n*16 + r] = accV[i][n][reg];  // i-major
            }
        }
        __syncthreads();

        if (t < DN) {
            const int col = t;
            const int ebase = half * 32;
            float s = 0.0f;
            int rstart = 0;
            for (int e = 0; e < 32; ++e) {
                s += accw[e*161 + col];
                const int ge = ebase + e;
                if (e == 31 || rowls[ge] != rowls[ge + 1]) {
                    float* dst = T + (size_t)rowls[ge] * DN + col;
                    if (rstart == 0 || e == 31) atomicAdd(dst, s);  // chunk-boundary run
                    else *dst = s;                                   // interior: exclusive
                    s = 0.0f; rstart = e + 1;
                }
            }
        }
        __syncthreads();
    }
}

// ---- node update: out = x + [f16(x), f16(T)] @ Wn + bu + deg*bc ----
template<int UXB>
__global__ __launch_bounds__(256) void node_kernel(
    const float* __restrict__ x, const unsigned short* __restrict__ xb,
    float* __restrict__ T, const int* __restrict__ cnt,
    const unsigned short* __restrict__ Wn,
    const float* __restrict__ bu, const float* __restrict__ bc)
{
    __shared__ __align__(16) unsigned short A[64][328];  // 160 x | 160 T (f16)
    const int t = threadIdx.x;
    const int nb = blockIdx.x * 64;

    if (UXB) {
        for (int j = t; j < 64 * 40; j += 256) {   // x-part straight f16 copy
            int m = j / 40, q = j - m * 40;
            int row = nb + m; if (row >= NN) row = NN - 1;
            const u16x4 v = *reinterpret_cast<const u16x4*>(xb + (size_t)row * DN + q * 4);
            *reinterpret_cast<u16x4*>(&A[m][q*4]) = v;
        }
    } else {
        for (int j = t; j < 64 * 40; j += 256) {
            int m = j / 40, q = j - m * 40;
            int row = nb + m; if (row >= NN) row = NN - 1;
            const float4 v = *reinterpret_cast<const float4*>(x + (size_t)row * DN + q * 4);
            u16x4 p; p[0] = f16bits(v.x); p[1] = f16bits(v.y); p[2] = f16bits(v.z); p[3] = f16bits(v.w);
            *reinterpret_cast<u16x4*>(&A[m][q*4]) = p;
        }
    }
    for (int j = t; j < 64 * 40; j += 256) {       // T-part with cvt
        int m = j / 40, q = j - m * 40;
        int row = nb + m; if (row >= NN) row = NN - 1;
        const float4 v = *reinterpret_cast<const float4*>(T + (size_t)row * DN + q * 4);
        u16x4 p; p[0] = f16bits(v.x); p[1] = f16bits(v.y); p[2] = f16bits(v.z); p[3] = f16bits(v.w);
        *reinterpret_cast<u16x4*>(&A[m][160 + q*4]) = p;
    }
    __syncthreads();

    const int lane = t & 63;
    const int wv = t >> 6;
    const int r = lane & 15, g = lane >> 4;
    const int er = wv * 16 + r;

    f32x4 acc[10];
    #pragma unroll
    for (int n = 0; n < 10; ++n) acc[n] = (f32x4){0.f, 0.f, 0.f, 0.f};

    for (int tk = 0; tk < 10; ++tk) {
        const f16x8 a = *reinterpret_cast<const f16x8*>(&A[er][32 * tk + 8 * g]);
        #pragma unroll
        for (int n = 0; n < 10; ++n) {
            const f16x8 b = *reinterpret_cast<const f16x8*>(Wn + ((size_t)(n * 10 + tk) * 64 + lane) * 8);
            acc[n] = __builtin_amdgcn_mfma_f32_16x16x32_f16(a, b, acc[n], 0, 0, 0);
        }
    }

    #pragma unroll
    for (int reg = 0; reg < 4; ++reg) {
        const int nrow = nb + wv * 16 + g * 4 + reg;
        if (nrow < NN) {
            const float dg = (float)cnt[nrow];
            #pragma unroll
            for (int n = 0; n < 10; ++n) {
                const int c = n * 16 + r;
                T[(size_t)nrow * DN + c] =
                    acc[n][reg] + x[(size_t)nrow * DN + c] + bu[c] + dg * bc[c];
            }
        }
    }
}

extern "C" void kernel_launch(void* const* d_in, const int* in_sizes, int n_in,
                              void* d_out, int out_size, void* d_ws, size_t ws_size,
                              hipStream_t stream) {
    const float* xf   = (const float*)d_in[0];
    const int*   eidx = (const int*)d_in[1];
    const float* ea   = (const float*)d_in[2];
    const float* W1 = (const float*)d_in[4];
    const float* W2 = (const float*)d_in[5];
    const float* W3 = (const float*)d_in[6];
    const float* W4 = (const float*)d_in[7];
    const float* Wm = (const float*)d_in[8];
    const float* bm = (const float*)d_in[9];
    const float* Wu = (const float*)d_in[10];
    const float* bu = (const float*)d_in[11];

    float* out = (float*)d_out;   // doubles as tp-accumulator T

    char* ws = (char*)d_ws;
    int*            cnt    = (int*)ws;                              // 200 KB
    int*            cursor = (int*)(ws + (256 << 10));              // 200 KB
    int*            sorted = (int*)(ws + (512 << 10));              // 3.2 MB
    int*            bsum   = (int*)(ws + (3968 << 10));             // 1 KB
    unsigned short* Wh     = (unsigned short*)(ws + (4096 << 10));  // 144 KB f16 edge W
    float*          Wc     = (float*)(ws + (4352 << 10));           // 100 KB
    float*          bc     = (float*)(ws + (4480 << 10));           // 640 B
    unsigned short* Wn     = (unsigned short*)(ws + (4608 << 10));  // 100 KB f16 node W
    unsigned short* xb     = (unsigned short*)(ws + (4864 << 10));  // 16 MB f16 x

    const bool uxb = ws_size >= ((size_t)(4864 + 16000) << 10);

    const int P1 = XPREP_B + WEDGE_B + WCOMP_B + ZERO_B;
    if (uxb) prep1_kernel<1><<<P1, 256, 0, stream>>>(xf, W1, W2, W3, W4, Wm, bm, Wu,
                                                     Wh, Wc, bc, xb, out, cnt);
    else     prep1_kernel<0><<<P1, 256, 0, stream>>>(xf, W1, W2, W3, W4, Wm, bm, Wu,
                                                     Wh, Wc, bc, xb, out, cnt);
    prep2_kernel<<<200 + NE / 256, 256, 0, stream>>>(Wu, Wc, Wn, eidx, cnt);
    scan1_kernel<<<NP / 256, 256, 0, stream>>>(cnt, cursor, bsum);
    scan2_kernel<<<1, 256, 0, stream>>>(bsum);
    scan3_kernel<<<NP / 256, 256, 0, stream>>>(cursor, bsum);
    scatter_kernel<<<NE / 256, 256, 0, stream>>>(eidx, cursor, sorted);
    if (uxb) {
        edge_kernel<1><<<NE / 64, 256, 0, stream>>>(xf, xb, eidx, ea, Wh, sorted, out);
        node_kernel<1><<<(NN + 63) / 64, 256, 0, stream>>>(xf, xb, out, cnt, Wn, bu, bc);
    } else {
        edge_kernel<0><<<NE / 64, 256, 0, stream>>>(xf, xb, eidx, ea, Wh, sorted, out);
        node_kernel<0><<<(NN + 63) / 64, 256, 0, stream>>>(xf, xb, out, cnt, Wn, bu, bc);
    }
}